// Round 18
// baseline (156.298 us; speedup 1.0000x reference)
//
#include <hip/hip_runtime.h>

typedef __attribute__((ext_vector_type(8))) short short8;
typedef __attribute__((ext_vector_type(4))) float f32x4;

constexpr int BCAP = 4096;   // padded per-bucket capacity in tmp (mean 2048, max ~2300)

__device__ __forceinline__ ushort rne_bf16(float f) {
  uint u = __float_as_uint(f);
  uint r = (u + 0x7FFFu + ((u >> 16) & 1u)) >> 16;
  return (ushort)r;
}
__device__ __forceinline__ float bf16_lo(uint pair) { return __uint_as_float(pair << 16); }
__device__ __forceinline__ float bf16_hi(uint pair) { return __uint_as_float(pair & 0xffff0000u); }
__device__ __forceinline__ float bf1(ushort v) { return __uint_as_float((uint)v << 16); }
__device__ __forceinline__ float lrelu(float a) { return a >= 0.f ? a : 0.2f * a; }

__device__ __forceinline__ uint lrelu_pair(uint pair) {
  float lo = lrelu(bf16_lo(pair));
  float hi = lrelu(bf16_hi(pair));
  return (uint)rne_bf16(lo) | ((uint)rne_bf16(hi) << 16);
}
__device__ __forceinline__ float4 lrelu_bf8(float4 v) {
  uint4 u = *(uint4*)&v;
  u.x = lrelu_pair(u.x); u.y = lrelu_pair(u.y);
  u.z = lrelu_pair(u.z); u.w = lrelu_pair(u.w);
  return *(float4*)&u;
}
__device__ __forceinline__ float4 pack_bf8(float4 a, float4 b) {
  uint u0 = (uint)rne_bf16(a.x) | ((uint)rne_bf16(a.y) << 16);
  uint u1 = (uint)rne_bf16(a.z) | ((uint)rne_bf16(a.w) << 16);
  uint u2 = (uint)rne_bf16(b.x) | ((uint)rne_bf16(b.y) << 16);
  uint u3 = (uint)rne_bf16(b.z) | ((uint)rne_bf16(b.w) << 16);
  uint4 r; r.x = u0; r.y = u1; r.z = u2; r.w = u3;
  return *(float4*)&r;
}

// (tile, y) decode: 16-block groups = 8 tiles x 2 y; tile's y-pair is 8 slots
// apart -> same XCD under round-robin dispatch -> shared A-panel hits L2.
__device__ __forceinline__ void decode_tile_y(int bid, int ngemm, int& tile, int& y) {
  int g = bid & 15;
  tile = (bid >> 4) * 8 + (g & 7);
  y = g >> 3;
  (void)ngemm;
}

// ---- fused prep: bucket-partition edges (LDS rank) | transpose-cast weights ----
__global__ __launch_bounds__(256) void prep_all_k(
    const int* __restrict__ ei, int E, int nEB,
    int* __restrict__ bcnt, uint2* __restrict__ tmp, int nbuck,
    const float* __restrict__ W1, const float* __restrict__ res1_w,
    const float* __restrict__ fc_w, const float* __restrict__ W2,
    ushort* __restrict__ Wt1, ushort* __restrict__ fcT, ushort* __restrict__ W2T)
{
  __shared__ int lcnt[400];
  __shared__ int gbase[400];
  const int tid = threadIdx.x, bid = blockIdx.x;
  const long gstride = (long)gridDim.x * 256;
  const long g0 = (long)bid * 256 + tid;

  if (bid < nEB) {
    for (int i = tid; i < nbuck; i += 256) lcnt[i] = 0;
    __syncthreads();
    const int ebase = bid * 4096;
    int srcs[16], dsts[16], rk[16];
#pragma unroll
    for (int i = 0; i < 16; ++i) {
      int e = ebase + i * 256 + tid;
      if (e < E) {
        srcs[i] = ei[e];
        dsts[i] = ei[E + e];
        rk[i] = atomicAdd(&lcnt[dsts[i] >> 7], 1);
      } else dsts[i] = -1;
    }
    __syncthreads();
    for (int b = tid; b < nbuck; b += 256)
      gbase[b] = lcnt[b] ? atomicAdd(&bcnt[b], lcnt[b]) : 0;
    __syncthreads();
#pragma unroll
    for (int i = 0; i < 16; ++i) {
      if (dsts[i] >= 0) {
        int b = dsts[i] >> 7;
        tmp[(size_t)b * BCAP + gbase[b] + rk[i]] = make_uint2((uint)srcs[i], (uint)dsts[i]);
      }
    }
  }

  for (long gi = g0; gi < 81920; gi += gstride) {
    const float* src; ushort* dst; int K, NO; long local;
    if (gi < 32768)            { src = W1;     dst = Wt1;          K = 256; NO = 128; local = gi; }
    else if (gi < 65536)       { src = res1_w; dst = Wt1 + 32768;  K = 256; NO = 128; local = gi - 32768; }
    else if (gi < 65536+8192)  { src = fc_w;   dst = fcT;          K = 128; NO = 64;  local = gi - 65536; }
    else                       { src = W2;     dst = W2T;          K = 128; NO = 64;  local = gi - 65536 - 8192; }
    int n = (int)(local / K), k = (int)(local % K);
    dst[local] = rne_bf16(src[(size_t)k * NO + n]);
  }
}

// ---- exclusive scan of bucket totals ----
__global__ __launch_bounds__(512) void scan_buckets_k(const int* __restrict__ bcnt,
                                                      int* __restrict__ bbase,
                                                      int* __restrict__ offp,
                                                      int nbuck, int N) {
  __shared__ int sh[512];
  int tid = threadIdx.x;
  int v = (tid < nbuck) ? bcnt[tid] : 0;
  sh[tid] = v;
  __syncthreads();
  for (int o = 1; o < 512; o <<= 1) {
    int t = (tid >= o) ? sh[tid - o] : 0;
    __syncthreads();
    sh[tid] += t;
    __syncthreads();
  }
  if (tid < nbuck) bbase[tid] = sh[tid] - v;
  if (tid == nbuck - 1) { bbase[nbuck] = sh[tid]; offp[N] = sh[tid]; }
}

// ---- L1 GEMM: BM=64, BN=128 (y picks W1|res1 half), 512thr, 27.6 KB LDS ----
__global__ __launch_bounds__(512) void gemm1_k(
    const float* __restrict__ x, const ushort* __restrict__ Wt1,
    const float* __restrict__ res1_b,
    const float* __restrict__ att_s1, const float* __restrict__ att_d1,
    ushort* __restrict__ h1bf, ushort* __restrict__ xresbf,
    float* __restrict__ a_s, float* __restrict__ a_d,
    const uint2* __restrict__ tmp, const int* __restrict__ bcnt,
    const int* __restrict__ bbase, int* __restrict__ offp,
    int* __restrict__ csr, int nbuck, int ngemm, int M)
{
  constexpr int LDA = 72;
  __shared__ ushort smem[64 * LDA + 128 * LDA];   // 27648 B
  int bid, y;
  decode_tile_y(blockIdx.x, ngemm, bid, y);
  if (bid >= ngemm) return;
  const int tid = threadIdx.x;
  ushort* As = smem;
  ushort* Bs = smem + 64 * LDA;
  const int w = tid >> 6, l = tid & 63;
  const int wr = w >> 2, wc = w & 3;
  const int l15 = l & 15, lg = l >> 4;
  const int row0 = bid * 64;
  const int srow = tid >> 3, sch = tid & 7;

  int gra = row0 + srow; if (gra >= M) gra = M - 1;
  const float*  Apf = x + (size_t)gra * 256 + sch * 8;
  const ushort* Bp  = Wt1 + ((size_t)y * 128 + srow) * 256 + sch * 8;

  f32x4 acc[2][2] = {};
  float4 raCa, raCb, rbC0, rbC1, raNa, raNb, rbN0, rbN1;
  raCa = *(const float4*)(Apf);
  raCb = *(const float4*)(Apf + 4);
  rbC0 = *(const float4*)(Bp);
  rbC1 = *(const float4*)(Bp + 64 * 256);

#pragma unroll
  for (int kt = 0; kt < 4; ++kt) {
    __syncthreads();
    *(float4*)&As[srow * LDA + sch * 8] = pack_bf8(raCa, raCb);
    *(float4*)&Bs[srow * LDA + sch * 8] = rbC0;
    *(float4*)&Bs[(64 + srow) * LDA + sch * 8] = rbC1;
    __syncthreads();
    if (kt < 3) {
      int k1 = (kt + 1) * 64;
      raNa = *(const float4*)(Apf + k1);
      raNb = *(const float4*)(Apf + k1 + 4);
      rbN0 = *(const float4*)(Bp + k1);
      rbN1 = *(const float4*)(Bp + 64 * 256 + k1);
    }
    short8 aF[2][2], bF[2][2];
#pragma unroll
    for (int m = 0; m < 2; ++m)
#pragma unroll
      for (int kk = 0; kk < 2; ++kk)
        aF[m][kk] = *(const short8*)&As[(wr * 32 + m * 16 + l15) * LDA + kk * 32 + lg * 8];
#pragma unroll
    for (int n = 0; n < 2; ++n)
#pragma unroll
      for (int kk = 0; kk < 2; ++kk)
        bF[n][kk] = *(const short8*)&Bs[(wc * 32 + n * 16 + l15) * LDA + kk * 32 + lg * 8];
#pragma unroll
    for (int m = 0; m < 2; ++m)
#pragma unroll
      for (int n = 0; n < 2; ++n)
#pragma unroll
        for (int kk = 0; kk < 2; ++kk)
          acc[m][n] = __builtin_amdgcn_mfma_f32_16x16x32_bf16(aF[m][kk], bF[n][kk], acc[m][n], 0, 0, 0);
    raCa = raNa; raCb = raNb; rbC0 = rbN0; rbC1 = rbN1;
  }
  __syncthreads();

  ushort* Cs = smem;
#pragma unroll
  for (int m = 0; m < 2; ++m)
#pragma unroll
    for (int n = 0; n < 2; ++n)
#pragma unroll
      for (int j = 0; j < 4; ++j) {
        int rl = wr * 32 + m * 16 + lg * 4 + j;
        int col = wc * 32 + n * 16 + l15;
        float v = acc[m][n][j] + (y ? res1_b[col] : 0.f);
        Cs[rl * 128 + col] = rne_bf16(v);
      }
  __syncthreads();

  if (y == 0) {
    int r = tid >> 3, s = tid & 7, h = s >> 1;
    int gr = row0 + r;
    float ps = 0.f, pd = 0.f;
#pragma unroll
    for (int i = 0; i < 16; ++i) {
      int col = s * 16 + i;
      float v = bf1(Cs[r * 128 + col]);
      ps += v * att_s1[h * 32 + (col & 31)];
      pd += v * att_d1[h * 32 + (col & 31)];
    }
    ps += __shfl_xor(ps, 1, 64);
    pd += __shfl_xor(pd, 1, 64);
    if (!(s & 1) && gr < M) { a_s[gr * 4 + h] = ps; a_d[gr * 4 + h] = pd; }
  }

  {
    ushort* out = y ? xresbf : h1bf;
#pragma unroll
    for (int idx = tid; idx < 1024; idx += 512) {
      int row = idx >> 4, c16 = idx & 15;
      int gr = row0 + row;
      if (gr < M)
        *(uint4*)&out[(size_t)gr * 128 + c16 * 8] = *(const uint4*)&Cs[row * 128 + c16 * 8];
    }
  }

  if (y == 1 && bid < nbuck) {
    __syncthreads();
    int* lcnt = (int*)smem;
    int* excl = lcnt + 128;
    const int vbase = bid * 128;
    const int nloc = ((vbase + 128 < M) ? 128 : M - vbase);
    const int cntb = bcnt[bid];
    const int bbase0 = bbase[bid];
    const uint2* bt = tmp + (size_t)bid * BCAP;
    if (tid < 128) lcnt[tid] = 0;
    __syncthreads();
    for (int e = tid; e < cntb; e += 512)
      atomicAdd(&lcnt[(int)bt[e].y - vbase], 1);
    __syncthreads();
    if (tid < 128) {
      int v = lcnt[tid];
      int sc = v;
#pragma unroll
      for (int o = 1; o < 64; o <<= 1) {
        int t = __shfl_up(sc, o, 64);
        if ((tid & 63) >= o) sc += t;
      }
      excl[tid] = sc - v;
    }
    __syncthreads();
    if (tid >= 64 && tid < 128) excl[tid] += excl[63] + lcnt[63];
    __syncthreads();
    if (tid < nloc) offp[vbase + tid] = bbase0 + excl[tid];
    if (tid < 128) lcnt[tid] = 0;
    __syncthreads();
    for (int e = tid; e < cntb; e += 512) {
      uint2 t = bt[e];
      int li = (int)t.y - vbase;
      int r = atomicAdd(&lcnt[li], 1);
      csr[bbase0 + excl[li] + r] = (int)t.x;
    }
  }
}

// ---- L2 GEMM (y: 0=hres=hpre@fc+b ; 1=h2=lrelu(hpre)@W2) + att2 ----
__global__ __launch_bounds__(512) void gemm2_k(
    const ushort* __restrict__ hpre,
    const ushort* __restrict__ fcT,            // W2T = fcT + 64*128
    const float* __restrict__ fc_b,
    const float* __restrict__ att_s2, const float* __restrict__ att_d2,
    ushort* __restrict__ hresb, ushort* __restrict__ h2bf,
    float* __restrict__ a_s, float* __restrict__ a_d, int ngemm, int M)
{
  constexpr int LDA = 72;
  __shared__ ushort smem[64 * LDA + 64 * LDA];
  int tile, y;
  decode_tile_y(blockIdx.x, ngemm, tile, y);
  if (tile >= ngemm) return;
  const int tid = threadIdx.x;
  const ushort* B = fcT + (size_t)y * 64 * 128;
  ushort* out = y ? h2bf : hresb;
  const int row0 = tile * 64;
  ushort* As = smem;
  ushort* Bs = smem + 64 * LDA;
  const int w = tid >> 6, l = tid & 63;
  const int wr = w >> 1, wc = w & 1;
  const int l15 = l & 15, lg = l >> 4;
  const int srow = tid >> 3, sch = tid & 7;

  int gra = row0 + srow; if (gra >= M) gra = M - 1;
  const ushort* Ap = hpre + (size_t)gra * 128 + sch * 8;
  const ushort* Bp = B + (size_t)srow * 128 + sch * 8;

  f32x4 acc[2] = {};
  float4 raC = *(const float4*)(Ap);
  float4 rbC = *(const float4*)(Bp);
  if (y) raC = lrelu_bf8(raC);
  float4 raN, rbN;

#pragma unroll
  for (int kt = 0; kt < 2; ++kt) {
    __syncthreads();
    *(float4*)&As[srow * LDA + sch * 8] = raC;
    *(float4*)&Bs[srow * LDA + sch * 8] = rbC;
    __syncthreads();
    if (kt < 1) {
      raN = *(const float4*)(Ap + 64);
      rbN = *(const float4*)(Bp + 64);
      if (y) raN = lrelu_bf8(raN);
    }

    short8 aF[2], bF[2][2];
#pragma unroll
    for (int kk = 0; kk < 2; ++kk)
      aF[kk] = *(const short8*)&As[(wr * 16 + l15) * LDA + kk * 32 + lg * 8];
#pragma unroll
    for (int n = 0; n < 2; ++n)
#pragma unroll
      for (int kk = 0; kk < 2; ++kk)
        bF[n][kk] = *(const short8*)&Bs[(wc * 32 + n * 16 + l15) * LDA + kk * 32 + lg * 8];
#pragma unroll
    for (int n = 0; n < 2; ++n)
#pragma unroll
      for (int kk = 0; kk < 2; ++kk)
        acc[n] = __builtin_amdgcn_mfma_f32_16x16x32_bf16(aF[kk], bF[n][kk], acc[n], 0, 0, 0);
    raC = raN; rbC = rbN;
  }
  __syncthreads();

  ushort* Cs = smem;
#pragma unroll
  for (int n = 0; n < 2; ++n)
#pragma unroll
    for (int j = 0; j < 4; ++j) {
      int rl = wr * 16 + lg * 4 + j;
      int col = wc * 32 + n * 16 + l15;
      float v = acc[n][j] + (y == 0 ? fc_b[col] : 0.f);
      Cs[rl * 64 + col] = rne_bf16(v);
    }
  __syncthreads();

  if (y == 1) {
    int r = tid >> 3, s = tid & 7;
    int gr = row0 + r;
    float ps = 0.f, pd = 0.f;
#pragma unroll
    for (int i = 0; i < 8; ++i) {
      int col = s * 8 + i;
      float v = bf1(Cs[r * 64 + col]);
      ps += v * att_s2[col];
      pd += v * att_d2[col];
    }
    ps += __shfl_xor(ps, 1, 64); pd += __shfl_xor(pd, 1, 64);
    ps += __shfl_xor(ps, 2, 64); pd += __shfl_xor(pd, 2, 64);
    ps += __shfl_xor(ps, 4, 64); pd += __shfl_xor(pd, 4, 64);
    if (s == 0 && gr < M) { a_s[gr] = ps; a_d[gr] = pd; }
  }

  {
    int row = tid >> 3, c16 = tid & 7;
    int gr = row0 + row;
    if (gr < M)
      *(uint4*)&out[(size_t)gr * 64 + c16 * 8] = *(const uint4*)&Cs[row * 64 + c16 * 8];
  }
}

// ---- aggregation: 256thr, software-pipelined weight chain ----
__global__ __launch_bounds__(256) void aggr1_k(const uint* __restrict__ h1u,
                                               const uint* __restrict__ xresu,
                                               const float* __restrict__ a_s,
                                               const float* __restrict__ a_d,
                                               const int* __restrict__ off,
                                               const int* __restrict__ csr,
                                               const float* __restrict__ b1,
                                               uint* __restrict__ hpreu, int n) {
  int w = threadIdx.x >> 6, l = threadIdx.x & 63;
  int d = blockIdx.x * 4 + w;
  if (d >= n) return;
  int h = l >> 4, c = l * 2;
  int le = l & 15, hb = l & 48;
  int s0 = off[d], s1 = off[d + 1];
  float adh = a_d[d * 4 + h];

  int p = s0;
  int idxN = 0; float wN = 0.f;
  if (p < s1) {
    int jp = p + le;
    int jc = jp < s1 ? jp : s1 - 1;
    idxN = csr[jc];
    wN = (jp < s1) ? __expf(lrelu(a_s[idxN * 4 + h] + adh)) : 0.f;
  }

  float ws = __expf(lrelu(a_s[d * 4 + h] + adh));   // self loop
  uint pd = h1u[(size_t)d * 64 + l];
  float lsum = ws, accx = ws * bf16_lo(pd), accy = ws * bf16_hi(pd);

  while (p < s1) {
    int idxC = idxN; float wC = wN;
    int pn = p + 16;
    if (pn < s1) {
      int jp = pn + le;
      int jc = jp < s1 ? jp : s1 - 1;
      idxN = csr[jc];
      wN = (jp < s1) ? __expf(lrelu(a_s[idxN * 4 + h] + adh)) : 0.f;
    }
    if (s1 - p >= 16) {
      float wi[16]; int sv[16];
#pragma unroll
      for (int i = 0; i < 16; ++i) {
        wi[i] = __shfl(wC, hb + i, 64);
        sv[i] = __shfl(idxC, i, 64);
      }
#pragma unroll
      for (int i = 0; i < 16; ++i) {
        uint q = h1u[(size_t)sv[i] * 64 + l];
        lsum += wi[i];
        accx += wi[i] * bf16_lo(q);
        accy += wi[i] * bf16_hi(q);
      }
    } else {
      int rem = s1 - p;
      for (int i = 0; i < rem; i += 4) {
#pragma unroll
        for (int j = 0; j < 4; ++j) {
          float wib = __shfl(wC, hb + i + j, 64);
          int svb = __shfl(idxC, i + j, 64);
          uint q = h1u[(size_t)svb * 64 + l];
          lsum += wib;
          accx += wib * bf16_lo(q);
          accy += wib * bf16_hi(q);
        }
      }
    }
    p = pn;
  }
  float inv = 1.f / (lsum + 1e-16f);
  uint xr = xresu[(size_t)d * 64 + l];
  float vx = accx * inv + b1[c] + bf16_lo(xr);
  float vy = accy * inv + b1[c + 1] + bf16_hi(xr);
  hpreu[(size_t)d * 64 + l] = (uint)rne_bf16(vx) | ((uint)rne_bf16(vy) << 16);
}

__global__ __launch_bounds__(256) void aggr2_k(const ushort* __restrict__ h2b,
                                               const ushort* __restrict__ hresb,
                                               const float* __restrict__ a_s,
                                               const float* __restrict__ a_d,
                                               const int* __restrict__ off,
                                               const int* __restrict__ csr,
                                               const float* __restrict__ b2,
                                               float* __restrict__ out, int n) {
  int w = threadIdx.x >> 6, l = threadIdx.x & 63;
  int d = blockIdx.x * 4 + w;
  if (d >= n) return;
  int le = l & 15;
  int s0 = off[d], s1 = off[d + 1];
  float adh = a_d[d];

  int p = s0;
  int idxN = 0; float wN = 0.f;
  if (p < s1) {
    int jp = p + le;
    int jc = jp < s1 ? jp : s1 - 1;
    idxN = csr[jc];
    wN = (jp < s1) ? __expf(lrelu(a_s[idxN] + adh)) : 0.f;
  }

  float ws = __expf(lrelu(a_s[d] + adh));
  float lsum = ws;
  float acc = ws * bf1(h2b[(size_t)d * 64 + l]);

  while (p < s1) {
    int idxC = idxN; float wC = wN;
    int pn = p + 16;
    if (pn < s1) {
      int jp = pn + le;
      int jc = jp < s1 ? jp : s1 - 1;
      idxN = csr[jc];
      wN = (jp < s1) ? __expf(lrelu(a_s[idxN] + adh)) : 0.f;
    }
    if (s1 - p >= 16) {
      float wi[16]; int sv[16];
#pragma unroll
      for (int i = 0; i < 16; ++i) {
        wi[i] = __shfl(wC, i, 64);
        sv[i] = __shfl(idxC, i, 64);
      }
#pragma unroll
      for (int i = 0; i < 16; ++i) {
        float fv = bf1(h2b[(size_t)sv[i] * 64 + l]);
        lsum += wi[i];
        acc += wi[i] * fv;
      }
    } else {
      int rem = s1 - p;
      for (int i = 0; i < rem; i += 4) {
#pragma unroll
        for (int j = 0; j < 4; ++j) {
          float wib = __shfl(wC, i + j, 64);
          int svb = __shfl(idxC, i + j, 64);
          float fv = bf1(h2b[(size_t)svb * 64 + l]);
          lsum += wib;
          acc += wib * fv;
        }
      }
    }
    p = pn;
  }
  float inv = 1.f / (lsum + 1e-16f);
  float z = acc * inv + b2[l] + bf1(hresb[(size_t)d * 64 + l]);
  out[(size_t)d * 64 + l] = lrelu(z);
}

// ---------------- launch ----------------
extern "C" void kernel_launch(void* const* d_in, const int* in_sizes, int n_in,
                              void* d_out, int out_size, void* d_ws, size_t ws_size,
                              hipStream_t stream) {
  const float* x        = (const float*)d_in[0];
  const int*   ei       = (const int*)d_in[1];
  const float* W1       = (const float*)d_in[2];
  const float* att_src1 = (const float*)d_in[3];
  const float* att_dst1 = (const float*)d_in[4];
  const float* b1       = (const float*)d_in[5];
  const float* W2       = (const float*)d_in[6];
  const float* att_src2 = (const float*)d_in[7];
  const float* att_dst2 = (const float*)d_in[8];
  const float* b2       = (const float*)d_in[9];
  const float* res1_w   = (const float*)d_in[10];
  const float* res1_b   = (const float*)d_in[11];
  const float* fc_w     = (const float*)d_in[12];
  const float* fc_b     = (const float*)d_in[13];
  float* out = (float*)d_out;

  const int N = in_sizes[0] / 256;
  const int E = in_sizes[1] / 2;
  const int nbuck = (N + 127) / 128;
  const int nEB = (E + 4095) / 4096;

  ushort* h1bf   = (ushort*)d_ws;                      // N*128
  ushort* xresbf = h1bf + (size_t)N * 128;             // N*128
  uint*   hpreu  = (uint*)(xresbf + (size_t)N * 128);  // N*64 uints
  float*  as1    = (float*)(hpreu + (size_t)N * 64);   // N*4
  float*  ad1    = as1 + (size_t)N * 4;                // N*4
  ushort* Wt1    = (ushort*)(ad1 + (size_t)N * 4);     // 256*256
  ushort* fcT    = Wt1 + 256 * 256;                    // 64*128
  ushort* W2T    = fcT + 64 * 128;                     // 64*128
  int* offp      = (int*)(W2T + 64 * 128);             // N+1
  int* csr       = offp + N + 1;                       // E
  int* bcnt      = csr + E;                            // 512
  int* bbase     = bcnt + 512;                         // 520
  uint2* tmp     = (uint2*)(((uintptr_t)(bbase + 520) + 7) & ~(uintptr_t)7);  // nbuck*BCAP
  // aliases
  ushort* h2bf   = h1bf;
  ushort* hresb  = xresbf;
  float*  as2 = as1, *ad2 = ad1;

  const int ngemm = (N + 63) / 64;
  const int gpair = 16 * ((ngemm + 7) / 8);   // padded (tile,y) grid

  hipMemsetAsync(bcnt, 0, 512 * 4, stream);
  prep_all_k<<<nEB, 256, 0, stream>>>(ei, E, nEB, bcnt, tmp, nbuck,
                                      W1, res1_w, fc_w, W2, Wt1, fcT, W2T);
  scan_buckets_k<<<1, 512, 0, stream>>>(bcnt, bbase, offp, nbuck, N);

  gemm1_k<<<gpair, 512, 0, stream>>>(x, Wt1, res1_b, att_src1, att_dst1,
                                     h1bf, xresbf, as1, ad1,
                                     tmp, bcnt, bbase, offp, csr, nbuck, ngemm, N);

  aggr1_k<<<(N + 3) / 4, 256, 0, stream>>>((const uint*)h1bf, (const uint*)xresbf, as1, ad1,
                                           offp, csr, b1, hpreu, N);

  gemm2_k<<<gpair, 512, 0, stream>>>(
      (const ushort*)hpreu, fcT, fc_b,
      att_src2, att_dst2, hresb, h2bf, as2, ad2, ngemm, N);

  aggr2_k<<<(N + 3) / 4, 256, 0, stream>>>(h2bf, hresb, as2, ad2, offp, csr, b2, out, N);
}

// Round 19
// 149.699 us; speedup vs baseline: 1.0441x; 1.0441x over previous
//
#include <hip/hip_runtime.h>

typedef __attribute__((ext_vector_type(8))) short short8;
typedef __attribute__((ext_vector_type(4))) float f32x4;

constexpr int BCAP = 4096;   // padded per-bucket capacity in tmp (mean 2048, max ~2300)

__device__ __forceinline__ ushort rne_bf16(float f) {
  uint u = __float_as_uint(f);
  uint r = (u + 0x7FFFu + ((u >> 16) & 1u)) >> 16;
  return (ushort)r;
}
__device__ __forceinline__ float bf16_lo(uint pair) { return __uint_as_float(pair << 16); }
__device__ __forceinline__ float bf16_hi(uint pair) { return __uint_as_float(pair & 0xffff0000u); }
__device__ __forceinline__ float bf1(ushort v) { return __uint_as_float((uint)v << 16); }
__device__ __forceinline__ float lrelu(float a) { return a >= 0.f ? a : 0.2f * a; }

__device__ __forceinline__ uint lrelu_pair(uint pair) {
  float lo = lrelu(bf16_lo(pair));
  float hi = lrelu(bf16_hi(pair));
  return (uint)rne_bf16(lo) | ((uint)rne_bf16(hi) << 16);
}
__device__ __forceinline__ float4 lrelu_bf8(float4 v) {
  uint4 u = *(uint4*)&v;
  u.x = lrelu_pair(u.x); u.y = lrelu_pair(u.y);
  u.z = lrelu_pair(u.z); u.w = lrelu_pair(u.w);
  return *(float4*)&u;
}
__device__ __forceinline__ float4 pack_bf8(float4 a, float4 b) {
  uint u0 = (uint)rne_bf16(a.x) | ((uint)rne_bf16(a.y) << 16);
  uint u1 = (uint)rne_bf16(a.z) | ((uint)rne_bf16(a.w) << 16);
  uint u2 = (uint)rne_bf16(b.x) | ((uint)rne_bf16(b.y) << 16);
  uint u3 = (uint)rne_bf16(b.z) | ((uint)rne_bf16(b.w) << 16);
  uint4 r; r.x = u0; r.y = u1; r.z = u2; r.w = u3;
  return *(float4*)&r;
}

// ---- fused prep: bucket-partition edges (LDS rank) | transpose-cast weights ----
__global__ __launch_bounds__(256) void prep_all_k(
    const int* __restrict__ ei, int E, int nEB,
    int* __restrict__ bcnt, uint2* __restrict__ tmp, int nbuck,
    const float* __restrict__ W1, const float* __restrict__ res1_w,
    const float* __restrict__ fc_w, const float* __restrict__ W2,
    ushort* __restrict__ Wt1, ushort* __restrict__ fcT, ushort* __restrict__ W2T)
{
  __shared__ int lcnt[400];
  __shared__ int gbase[400];
  const int tid = threadIdx.x, bid = blockIdx.x;
  const long gstride = (long)gridDim.x * 256;
  const long g0 = (long)bid * 256 + tid;

  if (bid < nEB) {
    for (int i = tid; i < nbuck; i += 256) lcnt[i] = 0;
    __syncthreads();
    const int ebase = bid * 4096;
    int srcs[16], dsts[16], rk[16];
#pragma unroll
    for (int i = 0; i < 16; ++i) {
      int e = ebase + i * 256 + tid;
      if (e < E) {
        srcs[i] = ei[e];
        dsts[i] = ei[E + e];
        rk[i] = atomicAdd(&lcnt[dsts[i] >> 7], 1);
      } else dsts[i] = -1;
    }
    __syncthreads();
    for (int b = tid; b < nbuck; b += 256)
      gbase[b] = lcnt[b] ? atomicAdd(&bcnt[b], lcnt[b]) : 0;
    __syncthreads();
#pragma unroll
    for (int i = 0; i < 16; ++i) {
      if (dsts[i] >= 0) {
        int b = dsts[i] >> 7;
        tmp[(size_t)b * BCAP + gbase[b] + rk[i]] = make_uint2((uint)srcs[i], (uint)dsts[i]);
      }
    }
  }

  for (long gi = g0; gi < 81920; gi += gstride) {
    const float* src; ushort* dst; int K, NO; long local;
    if (gi < 32768)            { src = W1;     dst = Wt1;          K = 256; NO = 128; local = gi; }
    else if (gi < 65536)       { src = res1_w; dst = Wt1 + 32768;  K = 256; NO = 128; local = gi - 32768; }
    else if (gi < 65536+8192)  { src = fc_w;   dst = fcT;          K = 128; NO = 64;  local = gi - 65536; }
    else                       { src = W2;     dst = W2T;          K = 128; NO = 64;  local = gi - 65536 - 8192; }
    int n = (int)(local / K), k = (int)(local % K);
    dst[local] = rne_bf16(src[(size_t)k * NO + n]);
  }
}

// ---- exclusive scan of bucket totals ----
__global__ __launch_bounds__(512) void scan_buckets_k(const int* __restrict__ bcnt,
                                                      int* __restrict__ bbase,
                                                      int* __restrict__ offp,
                                                      int nbuck, int N) {
  __shared__ int sh[512];
  int tid = threadIdx.x;
  int v = (tid < nbuck) ? bcnt[tid] : 0;
  sh[tid] = v;
  __syncthreads();
  for (int o = 1; o < 512; o <<= 1) {
    int t = (tid >= o) ? sh[tid - o] : 0;
    __syncthreads();
    sh[tid] += t;
    __syncthreads();
  }
  if (tid < nbuck) bbase[tid] = sh[tid] - v;
  if (tid == nbuck - 1) { bbase[nbuck] = sh[tid]; offp[N] = sh[tid]; }
}

// ---- L1 GEMM: BM=64, BN=128 (y picks W1|res1 half), 512thr, 27.6 KB LDS ----
__global__ __launch_bounds__(512) void gemm1_k(
    const float* __restrict__ x, const ushort* __restrict__ Wt1,
    const float* __restrict__ res1_b,
    const float* __restrict__ att_s1, const float* __restrict__ att_d1,
    ushort* __restrict__ h1bf, ushort* __restrict__ xresbf,
    float* __restrict__ a_s, float* __restrict__ a_d,
    const uint2* __restrict__ tmp, const int* __restrict__ bcnt,
    const int* __restrict__ bbase, int* __restrict__ offp,
    int* __restrict__ csr, int nbuck, int M)
{
  constexpr int LDA = 72;
  __shared__ ushort smem[64 * LDA + 128 * LDA];   // 27648 B
  const int bid = blockIdx.x, y = blockIdx.y, tid = threadIdx.x;
  ushort* As = smem;
  ushort* Bs = smem + 64 * LDA;
  const int w = tid >> 6, l = tid & 63;
  const int wr = w >> 2, wc = w & 3;
  const int l15 = l & 15, lg = l >> 4;
  const int row0 = bid * 64;
  const int srow = tid >> 3, sch = tid & 7;

  int gra = row0 + srow; if (gra >= M) gra = M - 1;
  const float*  Apf = x + (size_t)gra * 256 + sch * 8;
  const ushort* Bp  = Wt1 + ((size_t)y * 128 + srow) * 256 + sch * 8;

  f32x4 acc[2][2] = {};
  float4 raCa, raCb, rbC0, rbC1, raNa, raNb, rbN0, rbN1;
  raCa = *(const float4*)(Apf);
  raCb = *(const float4*)(Apf + 4);
  rbC0 = *(const float4*)(Bp);
  rbC1 = *(const float4*)(Bp + 64 * 256);

#pragma unroll
  for (int kt = 0; kt < 4; ++kt) {
    __syncthreads();
    *(float4*)&As[srow * LDA + sch * 8] = pack_bf8(raCa, raCb);
    *(float4*)&Bs[srow * LDA + sch * 8] = rbC0;
    *(float4*)&Bs[(64 + srow) * LDA + sch * 8] = rbC1;
    __syncthreads();
    if (kt < 3) {
      int k1 = (kt + 1) * 64;
      raNa = *(const float4*)(Apf + k1);
      raNb = *(const float4*)(Apf + k1 + 4);
      rbN0 = *(const float4*)(Bp + k1);
      rbN1 = *(const float4*)(Bp + 64 * 256 + k1);
    }
    short8 aF[2][2], bF[2][2];
#pragma unroll
    for (int m = 0; m < 2; ++m)
#pragma unroll
      for (int kk = 0; kk < 2; ++kk)
        aF[m][kk] = *(const short8*)&As[(wr * 32 + m * 16 + l15) * LDA + kk * 32 + lg * 8];
#pragma unroll
    for (int n = 0; n < 2; ++n)
#pragma unroll
      for (int kk = 0; kk < 2; ++kk)
        bF[n][kk] = *(const short8*)&Bs[(wc * 32 + n * 16 + l15) * LDA + kk * 32 + lg * 8];
#pragma unroll
    for (int m = 0; m < 2; ++m)
#pragma unroll
      for (int n = 0; n < 2; ++n)
#pragma unroll
        for (int kk = 0; kk < 2; ++kk)
          acc[m][n] = __builtin_amdgcn_mfma_f32_16x16x32_bf16(aF[m][kk], bF[n][kk], acc[m][n], 0, 0, 0);
    raCa = raNa; raCb = raNb; rbC0 = rbN0; rbC1 = rbN1;
  }
  __syncthreads();

  ushort* Cs = smem;
#pragma unroll
  for (int m = 0; m < 2; ++m)
#pragma unroll
    for (int n = 0; n < 2; ++n)
#pragma unroll
      for (int j = 0; j < 4; ++j) {
        int rl = wr * 32 + m * 16 + lg * 4 + j;
        int col = wc * 32 + n * 16 + l15;
        float v = acc[m][n][j] + (y ? res1_b[col] : 0.f);
        Cs[rl * 128 + col] = rne_bf16(v);
      }
  __syncthreads();

  if (y == 0) {
    int r = tid >> 3, s = tid & 7, h = s >> 1;
    int gr = row0 + r;
    float ps = 0.f, pd = 0.f;
#pragma unroll
    for (int i = 0; i < 16; ++i) {
      int col = s * 16 + i;
      float v = bf1(Cs[r * 128 + col]);
      ps += v * att_s1[h * 32 + (col & 31)];
      pd += v * att_d1[h * 32 + (col & 31)];
    }
    ps += __shfl_xor(ps, 1, 64);
    pd += __shfl_xor(pd, 1, 64);
    if (!(s & 1) && gr < M) { a_s[gr * 4 + h] = ps; a_d[gr * 4 + h] = pd; }
  }

  {
    ushort* out = y ? xresbf : h1bf;
#pragma unroll
    for (int idx = tid; idx < 1024; idx += 512) {
      int row = idx >> 4, c16 = idx & 15;
      int gr = row0 + row;
      if (gr < M)
        *(uint4*)&out[(size_t)gr * 128 + c16 * 8] = *(const uint4*)&Cs[row * 128 + c16 * 8];
    }
  }

  if (y == 1 && bid < nbuck) {
    __syncthreads();
    int* lcnt = (int*)smem;
    int* excl = lcnt + 128;
    const int vbase = bid * 128;
    const int nloc = ((vbase + 128 < M) ? 128 : M - vbase);
    const int cntb = bcnt[bid];
    const int bbase0 = bbase[bid];
    const uint2* bt = tmp + (size_t)bid * BCAP;
    if (tid < 128) lcnt[tid] = 0;
    __syncthreads();
    for (int e = tid; e < cntb; e += 512)
      atomicAdd(&lcnt[(int)bt[e].y - vbase], 1);
    __syncthreads();
    if (tid < 128) {
      int v = lcnt[tid];
      int sc = v;
#pragma unroll
      for (int o = 1; o < 64; o <<= 1) {
        int t = __shfl_up(sc, o, 64);
        if ((tid & 63) >= o) sc += t;
      }
      excl[tid] = sc - v;
    }
    __syncthreads();
    if (tid >= 64 && tid < 128) excl[tid] += excl[63] + lcnt[63];
    __syncthreads();
    if (tid < nloc) offp[vbase + tid] = bbase0 + excl[tid];
    if (tid < 128) lcnt[tid] = 0;
    __syncthreads();
    for (int e = tid; e < cntb; e += 512) {
      uint2 t = bt[e];
      int li = (int)t.y - vbase;
      int r = atomicAdd(&lcnt[li], 1);
      csr[bbase0 + excl[li] + r] = (int)t.x;
    }
  }
}

// ---- L2 GEMM (y: 0=hres=hpre@fc+b ; 1=h2=lrelu(hpre)@W2) + att2 ----
__global__ __launch_bounds__(512) void gemm2_k(
    const ushort* __restrict__ hpre,
    const ushort* __restrict__ fcT,            // W2T = fcT + 64*128
    const float* __restrict__ fc_b,
    const float* __restrict__ att_s2, const float* __restrict__ att_d2,
    ushort* __restrict__ hresb, ushort* __restrict__ h2bf,
    float* __restrict__ a_s, float* __restrict__ a_d, int M)
{
  constexpr int LDA = 72;
  __shared__ ushort smem[64 * LDA + 64 * LDA];
  const int tid = threadIdx.x, y = blockIdx.y;
  const ushort* B = fcT + (size_t)y * 64 * 128;
  ushort* out = y ? h2bf : hresb;
  const int row0 = blockIdx.x * 64;
  ushort* As = smem;
  ushort* Bs = smem + 64 * LDA;
  const int w = tid >> 6, l = tid & 63;
  const int wr = w >> 1, wc = w & 1;
  const int l15 = l & 15, lg = l >> 4;
  const int srow = tid >> 3, sch = tid & 7;

  int gra = row0 + srow; if (gra >= M) gra = M - 1;
  const ushort* Ap = hpre + (size_t)gra * 128 + sch * 8;
  const ushort* Bp = B + (size_t)srow * 128 + sch * 8;

  f32x4 acc[2] = {};
  float4 raC = *(const float4*)(Ap);
  float4 rbC = *(const float4*)(Bp);
  if (y) raC = lrelu_bf8(raC);
  float4 raN, rbN;

#pragma unroll
  for (int kt = 0; kt < 2; ++kt) {
    __syncthreads();
    *(float4*)&As[srow * LDA + sch * 8] = raC;
    *(float4*)&Bs[srow * LDA + sch * 8] = rbC;
    __syncthreads();
    if (kt < 1) {
      raN = *(const float4*)(Ap + 64);
      rbN = *(const float4*)(Bp + 64);
      if (y) raN = lrelu_bf8(raN);
    }

    short8 aF[2], bF[2][2];
#pragma unroll
    for (int kk = 0; kk < 2; ++kk)
      aF[kk] = *(const short8*)&As[(wr * 16 + l15) * LDA + kk * 32 + lg * 8];
#pragma unroll
    for (int n = 0; n < 2; ++n)
#pragma unroll
      for (int kk = 0; kk < 2; ++kk)
        bF[n][kk] = *(const short8*)&Bs[(wc * 32 + n * 16 + l15) * LDA + kk * 32 + lg * 8];
#pragma unroll
    for (int n = 0; n < 2; ++n)
#pragma unroll
      for (int kk = 0; kk < 2; ++kk)
        acc[n] = __builtin_amdgcn_mfma_f32_16x16x32_bf16(aF[kk], bF[n][kk], acc[n], 0, 0, 0);
    raC = raN; rbC = rbN;
  }
  __syncthreads();

  ushort* Cs = smem;
#pragma unroll
  for (int n = 0; n < 2; ++n)
#pragma unroll
    for (int j = 0; j < 4; ++j) {
      int rl = wr * 16 + lg * 4 + j;
      int col = wc * 32 + n * 16 + l15;
      float v = acc[n][j] + (y == 0 ? fc_b[col] : 0.f);
      Cs[rl * 64 + col] = rne_bf16(v);
    }
  __syncthreads();

  if (y == 1) {
    int r = tid >> 3, s = tid & 7;
    int gr = row0 + r;
    float ps = 0.f, pd = 0.f;
#pragma unroll
    for (int i = 0; i < 8; ++i) {
      int col = s * 8 + i;
      float v = bf1(Cs[r * 64 + col]);
      ps += v * att_s2[col];
      pd += v * att_d2[col];
    }
    ps += __shfl_xor(ps, 1, 64); pd += __shfl_xor(pd, 1, 64);
    ps += __shfl_xor(ps, 2, 64); pd += __shfl_xor(pd, 2, 64);
    ps += __shfl_xor(ps, 4, 64); pd += __shfl_xor(pd, 4, 64);
    if (s == 0 && gr < M) { a_s[gr] = ps; a_d[gr] = pd; }
  }

  {
    int row = tid >> 3, c16 = tid & 7;
    int gr = row0 + row;
    if (gr < M)
      *(uint4*)&out[(size_t)gr * 64 + c16 * 8] = *(const uint4*)&Cs[row * 64 + c16 * 8];
  }
}

// ---- aggregation: 256thr, software-pipelined weight chain ----
__global__ __launch_bounds__(256) void aggr1_k(const uint* __restrict__ h1u,
                                               const uint* __restrict__ xresu,
                                               const float* __restrict__ a_s,
                                               const float* __restrict__ a_d,
                                               const int* __restrict__ off,
                                               const int* __restrict__ csr,
                                               const float* __restrict__ b1,
                                               uint* __restrict__ hpreu, int n) {
  int w = threadIdx.x >> 6, l = threadIdx.x & 63;
  int d = blockIdx.x * 4 + w;
  if (d >= n) return;
  int h = l >> 4, c = l * 2;
  int le = l & 15, hb = l & 48;
  int s0 = off[d], s1 = off[d + 1];
  float adh = a_d[d * 4 + h];

  int p = s0;
  int idxN = 0; float wN = 0.f;
  if (p < s1) {
    int jp = p + le;
    int jc = jp < s1 ? jp : s1 - 1;
    idxN = csr[jc];
    wN = (jp < s1) ? __expf(lrelu(a_s[idxN * 4 + h] + adh)) : 0.f;
  }

  float ws = __expf(lrelu(a_s[d * 4 + h] + adh));   // self loop
  uint pd = h1u[(size_t)d * 64 + l];
  float lsum = ws, accx = ws * bf16_lo(pd), accy = ws * bf16_hi(pd);

  while (p < s1) {
    int idxC = idxN; float wC = wN;
    int pn = p + 16;
    if (pn < s1) {
      int jp = pn + le;
      int jc = jp < s1 ? jp : s1 - 1;
      idxN = csr[jc];
      wN = (jp < s1) ? __expf(lrelu(a_s[idxN * 4 + h] + adh)) : 0.f;
    }
    if (s1 - p >= 16) {
      float wi[16]; int sv[16];
#pragma unroll
      for (int i = 0; i < 16; ++i) {
        wi[i] = __shfl(wC, hb + i, 64);
        sv[i] = __shfl(idxC, i, 64);
      }
#pragma unroll
      for (int i = 0; i < 16; ++i) {
        uint q = h1u[(size_t)sv[i] * 64 + l];
        lsum += wi[i];
        accx += wi[i] * bf16_lo(q);
        accy += wi[i] * bf16_hi(q);
      }
    } else {
      int rem = s1 - p;
      for (int i = 0; i < rem; i += 4) {
#pragma unroll
        for (int j = 0; j < 4; ++j) {
          float wib = __shfl(wC, hb + i + j, 64);
          int svb = __shfl(idxC, i + j, 64);
          uint q = h1u[(size_t)svb * 64 + l];
          lsum += wib;
          accx += wib * bf16_lo(q);
          accy += wib * bf16_hi(q);
        }
      }
    }
    p = pn;
  }
  float inv = 1.f / (lsum + 1e-16f);
  uint xr = xresu[(size_t)d * 64 + l];
  float vx = accx * inv + b1[c] + bf16_lo(xr);
  float vy = accy * inv + b1[c + 1] + bf16_hi(xr);
  hpreu[(size_t)d * 64 + l] = (uint)rne_bf16(vx) | ((uint)rne_bf16(vy) << 16);
}

__global__ __launch_bounds__(256) void aggr2_k(const ushort* __restrict__ h2b,
                                               const ushort* __restrict__ hresb,
                                               const float* __restrict__ a_s,
                                               const float* __restrict__ a_d,
                                               const int* __restrict__ off,
                                               const int* __restrict__ csr,
                                               const float* __restrict__ b2,
                                               float* __restrict__ out, int n) {
  int w = threadIdx.x >> 6, l = threadIdx.x & 63;
  int d = blockIdx.x * 4 + w;
  if (d >= n) return;
  int le = l & 15;
  int s0 = off[d], s1 = off[d + 1];
  float adh = a_d[d];

  int p = s0;
  int idxN = 0; float wN = 0.f;
  if (p < s1) {
    int jp = p + le;
    int jc = jp < s1 ? jp : s1 - 1;
    idxN = csr[jc];
    wN = (jp < s1) ? __expf(lrelu(a_s[idxN] + adh)) : 0.f;
  }

  float ws = __expf(lrelu(a_s[d] + adh));
  float lsum = ws;
  float acc = ws * bf1(h2b[(size_t)d * 64 + l]);

  while (p < s1) {
    int idxC = idxN; float wC = wN;
    int pn = p + 16;
    if (pn < s1) {
      int jp = pn + le;
      int jc = jp < s1 ? jp : s1 - 1;
      idxN = csr[jc];
      wN = (jp < s1) ? __expf(lrelu(a_s[idxN] + adh)) : 0.f;
    }
    if (s1 - p >= 16) {
      float wi[16]; int sv[16];
#pragma unroll
      for (int i = 0; i < 16; ++i) {
        wi[i] = __shfl(wC, i, 64);
        sv[i] = __shfl(idxC, i, 64);
      }
#pragma unroll
      for (int i = 0; i < 16; ++i) {
        float fv = bf1(h2b[(size_t)sv[i] * 64 + l]);
        lsum += wi[i];
        acc += wi[i] * fv;
      }
    } else {
      int rem = s1 - p;
      for (int i = 0; i < rem; i += 4) {
#pragma unroll
        for (int j = 0; j < 4; ++j) {
          float wib = __shfl(wC, i + j, 64);
          int svb = __shfl(idxC, i + j, 64);
          float fv = bf1(h2b[(size_t)svb * 64 + l]);
          lsum += wib;
          acc += wib * fv;
        }
      }
    }
    p = pn;
  }
  float inv = 1.f / (lsum + 1e-16f);
  float z = acc * inv + b2[l] + bf1(hresb[(size_t)d * 64 + l]);
  out[(size_t)d * 64 + l] = lrelu(z);
}

// ---------------- launch ----------------
extern "C" void kernel_launch(void* const* d_in, const int* in_sizes, int n_in,
                              void* d_out, int out_size, void* d_ws, size_t ws_size,
                              hipStream_t stream) {
  const float* x        = (const float*)d_in[0];
  const int*   ei       = (const int*)d_in[1];
  const float* W1       = (const float*)d_in[2];
  const float* att_src1 = (const float*)d_in[3];
  const float* att_dst1 = (const float*)d_in[4];
  const float* b1       = (const float*)d_in[5];
  const float* W2       = (const float*)d_in[6];
  const float* att_src2 = (const float*)d_in[7];
  const float* att_dst2 = (const float*)d_in[8];
  const float* b2       = (const float*)d_in[9];
  const float* res1_w   = (const float*)d_in[10];
  const float* res1_b   = (const float*)d_in[11];
  const float* fc_w     = (const float*)d_in[12];
  const float* fc_b     = (const float*)d_in[13];
  float* out = (float*)d_out;

  const int N = in_sizes[0] / 256;
  const int E = in_sizes[1] / 2;
  const int nbuck = (N + 127) / 128;
  const int nEB = (E + 4095) / 4096;

  ushort* h1bf   = (ushort*)d_ws;                      // N*128
  ushort* xresbf = h1bf + (size_t)N * 128;             // N*128
  uint*   hpreu  = (uint*)(xresbf + (size_t)N * 128);  // N*64 uints
  float*  as1    = (float*)(hpreu + (size_t)N * 64);   // N*4
  float*  ad1    = as1 + (size_t)N * 4;                // N*4
  ushort* Wt1    = (ushort*)(ad1 + (size_t)N * 4);     // 256*256
  ushort* fcT    = Wt1 + 256 * 256;                    // 64*128
  ushort* W2T    = fcT + 64 * 128;                     // 64*128
  int* offp      = (int*)(W2T + 64 * 128);             // N+1
  int* csr       = offp + N + 1;                       // E
  int* bcnt      = csr + E;                            // 512
  int* bbase     = bcnt + 512;                         // 520
  uint2* tmp     = (uint2*)(((uintptr_t)(bbase + 520) + 7) & ~(uintptr_t)7);  // nbuck*BCAP
  // aliases
  ushort* h2bf   = h1bf;
  ushort* hresb  = xresbf;
  float*  as2 = as1, *ad2 = ad1;

  const int ngemm = (N + 63) / 64;

  hipMemsetAsync(bcnt, 0, 512 * 4, stream);
  prep_all_k<<<nEB, 256, 0, stream>>>(ei, E, nEB, bcnt, tmp, nbuck,
                                      W1, res1_w, fc_w, W2, Wt1, fcT, W2T);
  scan_buckets_k<<<1, 512, 0, stream>>>(bcnt, bbase, offp, nbuck, N);

  gemm1_k<<<dim3(ngemm, 2), 512, 0, stream>>>(x, Wt1, res1_b, att_src1, att_dst1,
                                              h1bf, xresbf, as1, ad1,
                                              tmp, bcnt, bbase, offp, csr, nbuck, N);

  aggr1_k<<<(N + 3) / 4, 256, 0, stream>>>((const uint*)h1bf, (const uint*)xresbf, as1, ad1,
                                           offp, csr, b1, hpreu, N);

  gemm2_k<<<dim3(ngemm, 2), 512, 0, stream>>>(
      (const ushort*)hpreu, fcT, fc_b,
      att_src2, att_dst2, hresb, h2bf, as2, ad2, N);

  aggr2_k<<<(N + 3) / 4, 256, 0, stream>>>(h2bf, hresb, as2, ad2, offp, csr, b2, out, N);
}